// Round 1
// baseline (325.811 us; speedup 1.0000x reference)
//
#include <hip/hip_runtime.h>
#include <math.h>

#define NN 100000
#define DIN 256
#define DH 128
#define GEMM_NB 1563       // ceil(NN/64)
#define BSHIFT 9
#define BNODES 512                     // nodes per bucket
#define NB_BUCKET 196                  // ceil(NN/512)
#define BCAP 12288                     // bucket capacity (mean 8163, sigma ~90)
#define PA_EDGES 8192                  // edges per pass-A block
#define PREP_NB 64                     // prepW blocks at 512 threads

using short8  = __attribute__((ext_vector_type(8))) short;
using float4v = __attribute__((ext_vector_type(4))) float;

static __device__ __forceinline__ unsigned short f2bf(float f) {
    unsigned u = __float_as_uint(f);
    unsigned r = u + 0x7fffu + ((u >> 16) & 1u);   // round-to-nearest-even
    return (unsigned short)(r >> 16);
}
static __device__ __forceinline__ float bf_lo(unsigned u) { return __uint_as_float(u << 16); }
static __device__ __forceinline__ float bf_hi(unsigned u) { return __uint_as_float(u & 0xffff0000u); }

// ---------------- fused: W1 pre-swizzle (blocks 0..63)  ||  pass A (blocks 64..) ----------------
// prepW slot t = (w8*8+ks)*64 + lane ; stores 8 bf16: j=0..7 of
// W1[(ks*32 + (lane>>4)*8 + j)*128 + w8*16 + (lane&15)]   (w8 = old wave*2+nt)
__global__ __launch_bounds__(512) void k_prep_partA(const float* __restrict__ W1,
                                                    unsigned short* __restrict__ W1p,
                                                    const int* __restrict__ src,
                                                    const int* __restrict__ dst, int E,
                                                    int* __restrict__ bucketFill,
                                                    int2* __restrict__ bucketArr) {
    __shared__ int aCnt[NB_BUCKET];
    __shared__ int aBase[NB_BUCKET];
    const int tid = threadIdx.x;

    if (blockIdx.x < PREP_NB) {
        // ---- prepW: identical t-space as the old 128x256 version ----
        int t = blockIdx.x * 512 + tid;             // 0..32767
        int lane = t & 63;
        int ks   = (t >> 6) & 7;
        int nt   = (t >> 9) & 1;
        int wv   = (t >> 10) & 3;
        int n = wv * 32 + nt * 16 + (lane & 15);
        int kbase = ks * 32 + (lane >> 4) * 8;
        short8 v;
#pragma unroll
        for (int j = 0; j < 8; ++j) v[j] = (short)f2bf(W1[(kbase + j) * DH + n]);
        *(short8*)&W1p[(long long)t * 8] = v;
        return;
    }

    // ---- pass A: partition 8192 edges into dst-range buckets ----
    const int ba = blockIdx.x - PREP_NB;
    for (int i = tid; i < NB_BUCKET; i += 512) aCnt[i] = 0;
    __syncthreads();
    const int e0   = ba * PA_EDGES;
    const int eend = min(e0 + PA_EDGES, E);
    for (int e = e0 + tid; e < eend; e += 512)
        atomicAdd(&aCnt[dst[e] >> BSHIFT], 1);
    __syncthreads();
    for (int i = tid; i < NB_BUCKET; i += 512) {
        int c = aCnt[i];
        aBase[i] = c ? atomicAdd(&bucketFill[i], c) : 0;
        aCnt[i] = 0;   // reuse as cursor
    }
    __syncthreads();
    for (int e = e0 + tid; e < eend; e += 512) {
        int d = dst[e];
        int b = d >> BSHIFT;
        int r = atomicAdd(&aCnt[b], 1);
        bucketArr[(long long)b * BCAP + aBase[b] + r] = make_int2(src[e], d);
    }
}

// ---------------- fused: pass B (blocks 0..195)  ||  GEMM hs=x@W1 (blocks 196..) ----------------
__global__ __launch_bounds__(512) void k_gemm_partB(const float* __restrict__ x,
                                                    const unsigned short* __restrict__ W1p,
                                                    unsigned short* __restrict__ hs,
                                                    const int* __restrict__ bucketFill,
                                                    const int2* __restrict__ bucketArr,
                                                    int* __restrict__ cnt,
                                                    int* __restrict__ excl,
                                                    float* __restrict__ dinv,
                                                    int* __restrict__ eidx) {
    __shared__ unsigned short aL[64 * 32 * 8];   // 32 KB (gemm path)
    __shared__ int h[BNODES];                    // partB path
    __shared__ int hex[BNODES];
    __shared__ int st[256];
    const int tid = threadIdx.x;

    if (blockIdx.x < NB_BUCKET) {
        // ---- pass B: per-bucket local CSR build ----
        const int b     = blockIdx.x;
        const int nbase = b << BSHIFT;
        const int len   = bucketFill[b];
        const long long abase = (long long)b * BCAP;

        // gbase = sum(bucketFill[0..b-1]) via block reduction
        if (tid < 256) st[tid] = (tid < b) ? bucketFill[tid] : 0;
        __syncthreads();
        for (int off = 128; off > 0; off >>= 1) {
            if (tid < off) st[tid] += st[tid + off];
            __syncthreads();
        }
        const int gbase = st[0];
        __syncthreads();

        for (int i = tid; i < BNODES; i += 512) h[i] = 0;
        __syncthreads();
        for (int k = tid; k < len; k += 512)
            atomicAdd(&h[bucketArr[abase + k].y - nbase], 1);
        __syncthreads();

        // scan 512 counters: pairwise + Hillis-Steele over 256 pair sums
        int a0 = 0, a1 = 0;
        if (tid < 256) {
            a0 = h[2 * tid]; a1 = h[2 * tid + 1];
            st[tid] = a0 + a1;
        }
        __syncthreads();
        for (int off = 1; off < 256; off <<= 1) {
            int val = (tid < 256 && tid >= off) ? st[tid - off] : 0;
            __syncthreads();
            if (tid < 256) st[tid] += val;
            __syncthreads();
        }
        if (tid < 256) {
            int prev = (tid > 0) ? st[tid - 1] : 0;
            hex[2 * tid]     = prev;
            hex[2 * tid + 1] = prev + a0;
        }
        __syncthreads();

        for (int i = tid; i < BNODES; i += 512) {
            int n = nbase + i;
            if (n < NN) {
                int c = h[i];
                cnt[n]  = c;
                excl[n] = gbase + hex[i];
                dinv[n] = rsqrtf(1.0f + (float)c);
            }
        }
        for (int i = tid; i < BNODES; i += 512) h[i] = 0;   // cursors
        __syncthreads();

        for (int k = tid; k < len; k += 512) {
            int2 p = bucketArr[abase + k];
            int li = p.y - nbase;
            int r = atomicAdd(&h[li], 1);
            eidx[gbase + hex[li] + r] = p.x;
        }
        return;
    }

    // ---- GEMM (MFMA bf16), 512 threads / 8 waves; wave w8 = old (wave,nt) pair ----
    const int bid  = blockIdx.x - NB_BUCKET;
    const int w8   = tid >> 6;          // 0..7 -> output cols [w8*16, w8*16+16)
    const int lane = tid & 63;
    const int quad = lane >> 4;
    const int m16  = lane & 15;
    const int row0 = bid * 64;

    // coalesced fragment loads: 8 x 16B per thread (same W1p slots as before)
    short8 bfr[8];
#pragma unroll
    for (int ks = 0; ks < 8; ++ks)
        bfr[ks] = ((const short8*)W1p)[(w8 * 8 + ks) * 64 + lane];

    // stage A tile -> bf16 LDS, swizzled (same layout as validated 256-thread version)
#pragma unroll
    for (int it = 0; it < 4; ++it) {
        int id  = it * 512 + tid;
        int row = id >> 5;
        int kb  = id & 31;
        int gr  = row0 + row;
        float4 f0, f1;
        if (gr < NN) {
            const float* xp = &x[(long long)gr * DIN + kb * 8];
            f0 = *(const float4*)xp;
            f1 = *(const float4*)(xp + 4);
        } else {
            f0 = make_float4(0.f, 0.f, 0.f, 0.f);
            f1 = f0;
        }
        short8 v;
        v[0] = (short)f2bf(f0.x); v[1] = (short)f2bf(f0.y);
        v[2] = (short)f2bf(f0.z); v[3] = (short)f2bf(f0.w);
        v[4] = (short)f2bf(f1.x); v[5] = (short)f2bf(f1.y);
        v[6] = (short)f2bf(f1.z); v[7] = (short)f2bf(f1.w);
        int chunk = row * 32 + (kb ^ (row & 31));
        *(short8*)&aL[chunk * 8] = v;
    }
    __syncthreads();

    float4v acc[4];
#pragma unroll
    for (int mt = 0; mt < 4; ++mt) acc[mt] = (float4v)(0.0f);

#pragma unroll
    for (int mt = 0; mt < 4; ++mt) {
        int row = mt * 16 + m16;
#pragma unroll
        for (int ks = 0; ks < 8; ++ks) {
            int kb = ks * 4 + quad;
            int chunk = row * 32 + (kb ^ (row & 31));
            short8 a = *(const short8*)&aL[chunk * 8];
            acc[mt] = __builtin_amdgcn_mfma_f32_16x16x32_bf16(a, bfr[ks], acc[mt], 0, 0, 0);
        }
    }

    const int n0 = w8 * 16;
#pragma unroll
    for (int mt = 0; mt < 4; ++mt) {
#pragma unroll
        for (int r = 0; r < 4; ++r) {
            int row = row0 + mt * 16 + quad * 4 + r;
            if (row < NN)
                hs[(long long)row * DH + n0 + m16] = f2bf(acc[mt][r]);
        }
    }
}

// ---------------- fused layer-1 aggregation + layer-2 linear: one wave per node ----------------
// Edge indices fetched cooperatively (one vector load / 16 edges), broadcast to SGPR via
// v_readlane so dinv becomes a scalar load and the hs row gather uses scalar-base addressing.
__global__ __launch_bounds__(256) void k_agg1l2(const int* __restrict__ eidx,
                                                const int* __restrict__ excl,   // absolute
                                                const int* __restrict__ cnt,
                                                const unsigned* __restrict__ hs2,
                                                const float* __restrict__ dinv,
                                                const float* __restrict__ b1,
                                                const float* __restrict__ W2,
                                                float* __restrict__ zs) {
    int w = (blockIdx.x * 256 + threadIdx.x) >> 6;
    if (w >= NN) return;
    int lane = threadIdx.x & 63;
    int offs = __builtin_amdgcn_readfirstlane(excl[w]);
    int c    = __builtin_amdgcn_readfirstlane(cnt[w]);

    float dw = dinv[w];
    unsigned u = hs2[(long long)w * 64 + lane];   // self-loop
    float ax = dw * bf_lo(u);
    float ay = dw * bf_hi(u);

    const int l16 = lane & 15;
    for (int j = 0; j < c; j += 16) {
        int rem = c - j; if (rem > 16) rem = 16;          // uniform
        int idx = offs + j + ((l16 < rem) ? l16 : 0);     // clamp OOB lanes to a valid slot
        int sv = eidx[idx];                                // 1 vector load / 16 edges
        float es[16]; unsigned uu[16];
#pragma unroll
        for (int q = 0; q < 16; ++q) if (q < rem) {
            int sq = __builtin_amdgcn_readlane(sv, q);     // SGPR src index
            es[q] = dinv[sq];                              // uniform addr -> scalar load
            uu[q] = hs2[(long long)sq * 64 + lane];        // scalar base + lane*4
        }
#pragma unroll
        for (int q = 0; q < 16; ++q) if (q < rem) {
            ax = fmaf(es[q], bf_lo(uu[q]), ax);
            ay = fmaf(es[q], bf_hi(uu[q]), ay);
        }
    }

    float2 bb = ((const float2*)b1)[lane];
    float2 ww = ((const float2*)W2)[lane];
    float r0 = fmaxf(fmaf(dw, ax, bb.x), 0.0f);
    float r1 = fmaxf(fmaf(dw, ay, bb.y), 0.0f);
    float v = r0 * ww.x + r1 * ww.y;
#pragma unroll
    for (int off = 32; off > 0; off >>= 1) v += __shfl_down(v, off);
    if (lane == 0) zs[w] = v * dw;
}

// ---------------- layer-2 aggregation + sigmoid epilogue (ILP-4) ----------------
__global__ void k_agg2_final(const int* __restrict__ eidx,
                             const int* __restrict__ excl,   // absolute
                             const int* __restrict__ cnt,
                             const float* __restrict__ zs,
                             const float* __restrict__ dinv,
                             const float* __restrict__ b2,
                             float* __restrict__ out) {
    int i = blockIdx.x * 256 + threadIdx.x;
    if (i >= NN) return;
    int offs = excl[i];
    int c = cnt[i];
    float v = zs[i];   // self-loop
    int j = 0;
    for (; j + 3 < c; j += 4) {
        int s0 = eidx[offs + j + 0];
        int s1 = eidx[offs + j + 1];
        int s2 = eidx[offs + j + 2];
        int s3 = eidx[offs + j + 3];
        v += zs[s0] + zs[s1] + zs[s2] + zs[s3];
    }
    for (; j < c; ++j) v += zs[eidx[offs + j]];
    float z = fmaf(dinv[i], v, b2[0]);
    out[i] = 1.0f / (1.0f + __expf(-z));
}

extern "C" void kernel_launch(void* const* d_in, const int* in_sizes, int n_in,
                              void* d_out, int out_size, void* d_ws, size_t ws_size,
                              hipStream_t stream) {
    const float* x  = (const float*)d_in[0];
    const int*   ei = (const int*)d_in[1];
    const float* W1 = (const float*)d_in[2];
    const float* b1 = (const float*)d_in[3];
    const float* W2 = (const float*)d_in[4];
    const float* b2 = (const float*)d_in[5];
    float* out = (float*)d_out;

    const int E = in_sizes[1] / 2;
    const int* src = ei;
    const int* dst = ei + E;

    // workspace layout (4-byte units; bucketArr 8B-aligned, hs 16B-aligned)
    int* wsi = (int*)d_ws;
    float* dinv       = (float*)wsi;                 // N
    int*   cnt        = wsi + NN;                    // N
    int*   excl       = cnt + NN;                    // N
    float* zs         = (float*)(excl + NN);         // N
    int*   bucketFill = (int*)(zs + NN);             // 256
    unsigned short* W1p = (unsigned short*)(bucketFill + 256);  // 32768 bf16 (= 16384 ints)
    int*   eidx       = (int*)(W1p + 32768);         // E
    int2*  bucketArr  = (int2*)(eidx + E);           // NB_BUCKET*BCAP pairs (~19.3 MB)
    unsigned short* hs = (unsigned short*)(bucketArr + (long long)NB_BUCKET * BCAP);  // N*128 bf16

    const int nb_nodes = (NN + 255) / 256;
    const int pa_nb = (E + PA_EDGES - 1) / PA_EDGES;

    hipMemsetAsync(bucketFill, 0, NB_BUCKET * sizeof(int), stream);

    // launch 1: prepW (64 blocks) || partA (pa_nb blocks) — independent roots
    k_prep_partA<<<PREP_NB + pa_nb, 512, 0, stream>>>(W1, W1p, src, dst, E,
                                                      bucketFill, bucketArr);
    // launch 2: partB (196 blocks) || gemm (1563 blocks) — independent chains overlap
    k_gemm_partB<<<NB_BUCKET + GEMM_NB, 512, 0, stream>>>(x, W1p, hs, bucketFill, bucketArr,
                                                          cnt, excl, dinv, eidx);

    k_agg1l2<<<(NN * 64 + 255) / 256, 256, 0, stream>>>(eidx, excl, cnt,
                                                        (const unsigned*)hs, dinv, b1, W2, zs);

    k_agg2_final<<<nb_nodes, 256, 0, stream>>>(eidx, excl, cnt, zs, dinv, b2, out);
}

// Round 2
// 288.180 us; speedup vs baseline: 1.1306x; 1.1306x over previous
//
#include <hip/hip_runtime.h>
#include <math.h>

#define NN 100000
#define DIN 256
#define DH 128
#define GEMM_NB 1563       // ceil(NN/64)
#define BSHIFT 9
#define BNODES 512                     // nodes per bucket
#define NB_BUCKET 196                  // ceil(NN/512)
#define BCAP 12288                     // bucket capacity (mean 8163, sigma ~90)
#define PA_EDGES 8192                  // edges per pass-A block
#define PREP_NB 64                     // prepW blocks at 512 threads

using short8  = __attribute__((ext_vector_type(8))) short;
using float4v = __attribute__((ext_vector_type(4))) float;

static __device__ __forceinline__ unsigned short f2bf(float f) {
    unsigned u = __float_as_uint(f);
    unsigned r = u + 0x7fffu + ((u >> 16) & 1u);   // round-to-nearest-even
    return (unsigned short)(r >> 16);
}
static __device__ __forceinline__ float bf_lo(unsigned u) { return __uint_as_float(u << 16); }
static __device__ __forceinline__ float bf_hi(unsigned u) { return __uint_as_float(u & 0xffff0000u); }

// ---------------- fused: W1 pre-swizzle (blocks 0..63)  ||  pass A (blocks 64..) ----------------
__global__ __launch_bounds__(512) void k_prep_partA(const float* __restrict__ W1,
                                                    unsigned short* __restrict__ W1p,
                                                    const int* __restrict__ src,
                                                    const int* __restrict__ dst, int E,
                                                    int* __restrict__ bucketFill,
                                                    int2* __restrict__ bucketArr) {
    __shared__ int aCnt[NB_BUCKET];
    __shared__ int aBase[NB_BUCKET];
    const int tid = threadIdx.x;

    if (blockIdx.x < PREP_NB) {
        // ---- prepW: identical t-space as the validated 128x256 version ----
        int t = blockIdx.x * 512 + tid;             // 0..32767
        int lane = t & 63;
        int ks   = (t >> 6) & 7;
        int nt   = (t >> 9) & 1;
        int wv   = (t >> 10) & 3;
        int n = wv * 32 + nt * 16 + (lane & 15);
        int kbase = ks * 32 + (lane >> 4) * 8;
        short8 v;
#pragma unroll
        for (int j = 0; j < 8; ++j) v[j] = (short)f2bf(W1[(kbase + j) * DH + n]);
        *(short8*)&W1p[(long long)t * 8] = v;
        return;
    }

    // ---- pass A: partition 8192 edges into dst-range buckets ----
    const int ba = blockIdx.x - PREP_NB;
    for (int i = tid; i < NB_BUCKET; i += 512) aCnt[i] = 0;
    __syncthreads();
    const int e0   = ba * PA_EDGES;
    const int eend = min(e0 + PA_EDGES, E);
    for (int e = e0 + tid; e < eend; e += 512)
        atomicAdd(&aCnt[dst[e] >> BSHIFT], 1);
    __syncthreads();
    for (int i = tid; i < NB_BUCKET; i += 512) {
        int c = aCnt[i];
        aBase[i] = c ? atomicAdd(&bucketFill[i], c) : 0;
        aCnt[i] = 0;   // reuse as cursor
    }
    __syncthreads();
    for (int e = e0 + tid; e < eend; e += 512) {
        int d = dst[e];
        int b = d >> BSHIFT;
        int r = atomicAdd(&aCnt[b], 1);
        bucketArr[(long long)b * BCAP + aBase[b] + r] = make_int2(src[e], d);
    }
}

// ---------------- fused: pass B (blocks 0..195)  ||  GEMM hs=x@W1 (blocks 196..) ----------------
__global__ __launch_bounds__(512) void k_gemm_partB(const float* __restrict__ x,
                                                    const unsigned short* __restrict__ W1p,
                                                    unsigned short* __restrict__ hs,
                                                    const int* __restrict__ bucketFill,
                                                    const int2* __restrict__ bucketArr,
                                                    int* __restrict__ cnt,
                                                    int* __restrict__ excl,
                                                    float* __restrict__ dinv,
                                                    int* __restrict__ eidx) {
    __shared__ unsigned short aL[64 * 32 * 8];   // 32 KB (gemm path)
    __shared__ int h[BNODES];                    // partB path
    __shared__ int hex[BNODES];
    __shared__ int st[256];
    const int tid = threadIdx.x;

    if (blockIdx.x < NB_BUCKET) {
        // ---- pass B: per-bucket local CSR build ----
        const int b     = blockIdx.x;
        const int nbase = b << BSHIFT;
        const int len   = bucketFill[b];
        const long long abase = (long long)b * BCAP;

        // gbase = sum(bucketFill[0..b-1]) via block reduction
        if (tid < 256) st[tid] = (tid < b) ? bucketFill[tid] : 0;
        __syncthreads();
        for (int off = 128; off > 0; off >>= 1) {
            if (tid < off) st[tid] += st[tid + off];
            __syncthreads();
        }
        const int gbase = st[0];
        __syncthreads();

        for (int i = tid; i < BNODES; i += 512) h[i] = 0;
        __syncthreads();
        for (int k = tid; k < len; k += 512)
            atomicAdd(&h[bucketArr[abase + k].y - nbase], 1);
        __syncthreads();

        // scan 512 counters: pairwise + Hillis-Steele over 256 pair sums
        int a0 = 0, a1 = 0;
        if (tid < 256) {
            a0 = h[2 * tid]; a1 = h[2 * tid + 1];
            st[tid] = a0 + a1;
        }
        __syncthreads();
        for (int off = 1; off < 256; off <<= 1) {
            int val = (tid < 256 && tid >= off) ? st[tid - off] : 0;
            __syncthreads();
            if (tid < 256) st[tid] += val;
            __syncthreads();
        }
        if (tid < 256) {
            int prev = (tid > 0) ? st[tid - 1] : 0;
            hex[2 * tid]     = prev;
            hex[2 * tid + 1] = prev + a0;
        }
        __syncthreads();

        for (int i = tid; i < BNODES; i += 512) {
            int n = nbase + i;
            if (n < NN) {
                int c = h[i];
                cnt[n]  = c;
                excl[n] = gbase + hex[i];
                dinv[n] = rsqrtf(1.0f + (float)c);
            }
        }
        for (int i = tid; i < BNODES; i += 512) h[i] = 0;   // cursors
        __syncthreads();

        for (int k = tid; k < len; k += 512) {
            int2 p = bucketArr[abase + k];
            int li = p.y - nbase;
            int r = atomicAdd(&h[li], 1);
            eidx[gbase + hex[li] + r] = p.x;
        }
        return;
    }

    // ---- GEMM (MFMA bf16), 512 threads / 8 waves; wave w8 = old (wave,nt) pair ----
    const int bid  = blockIdx.x - NB_BUCKET;
    const int w8   = tid >> 6;          // 0..7 -> output cols [w8*16, w8*16+16)
    const int lane = tid & 63;
    const int quad = lane >> 4;
    const int m16  = lane & 15;
    const int row0 = bid * 64;

    // coalesced fragment loads: 8 x 16B per thread (same W1p slots as before)
    short8 bfr[8];
#pragma unroll
    for (int ks = 0; ks < 8; ++ks)
        bfr[ks] = ((const short8*)W1p)[(w8 * 8 + ks) * 64 + lane];

    // stage A tile -> bf16 LDS, swizzled
#pragma unroll
    for (int it = 0; it < 4; ++it) {
        int id  = it * 512 + tid;
        int row = id >> 5;
        int kb  = id & 31;
        int gr  = row0 + row;
        float4 f0, f1;
        if (gr < NN) {
            const float* xp = &x[(long long)gr * DIN + kb * 8];
            f0 = *(const float4*)xp;
            f1 = *(const float4*)(xp + 4);
        } else {
            f0 = make_float4(0.f, 0.f, 0.f, 0.f);
            f1 = f0;
        }
        short8 v;
        v[0] = (short)f2bf(f0.x); v[1] = (short)f2bf(f0.y);
        v[2] = (short)f2bf(f0.z); v[3] = (short)f2bf(f0.w);
        v[4] = (short)f2bf(f1.x); v[5] = (short)f2bf(f1.y);
        v[6] = (short)f2bf(f1.z); v[7] = (short)f2bf(f1.w);
        int chunk = row * 32 + (kb ^ (row & 31));
        *(short8*)&aL[chunk * 8] = v;
    }
    __syncthreads();

    float4v acc[4];
#pragma unroll
    for (int mt = 0; mt < 4; ++mt) acc[mt] = (float4v)(0.0f);

#pragma unroll
    for (int mt = 0; mt < 4; ++mt) {
        int row = mt * 16 + m16;
#pragma unroll
        for (int ks = 0; ks < 8; ++ks) {
            int kb = ks * 4 + quad;
            int chunk = row * 32 + (kb ^ (row & 31));
            short8 a = *(const short8*)&aL[chunk * 8];
            acc[mt] = __builtin_amdgcn_mfma_f32_16x16x32_bf16(a, bfr[ks], acc[mt], 0, 0, 0);
        }
    }

    const int n0 = w8 * 16;
#pragma unroll
    for (int mt = 0; mt < 4; ++mt) {
#pragma unroll
        for (int r = 0; r < 4; ++r) {
            int row = row0 + mt * 16 + quad * 4 + r;
            if (row < NN)
                hs[(long long)row * DH + n0 + m16] = f2bf(acc[mt][r]);
        }
    }
}

// ---------------- fused layer-1 aggregation + layer-2 linear: one wave per node ----------------
// Edge-paired gather: wave halves (32 lanes each) process two edges at once; each lane owns
// 4 features (one uint2 = 4 bf16). All loads stay per-lane VMEM (independent, MLP-friendly).
// Halves are combined with shfl_xor(32) before the ReLU nonlinearity.
__global__ __launch_bounds__(256) void k_agg1l2(const int* __restrict__ eidx,
                                                const int* __restrict__ excl,   // absolute
                                                const int* __restrict__ cnt,
                                                const unsigned* __restrict__ hs2,
                                                const float* __restrict__ dinv,
                                                const float* __restrict__ b1,
                                                const float* __restrict__ W2,
                                                float* __restrict__ zs) {
    int w = (blockIdx.x * 256 + threadIdx.x) >> 6;
    if (w >= NN) return;
    const int lane = threadIdx.x & 63;
    const int hh   = lane >> 5;          // half id: 0 = even edges, 1 = odd edges
    const int l5   = lane & 31;
    int offs = excl[w];
    int c    = cnt[w];

    float dw = dinv[w];
    const uint2* hrow = (const uint2*)hs2;   // row stride 32 uint2

    // self-loop: only low half contributes (halves are summed later)
    uint2 su = hrow[(long long)w * 32 + l5];
    float ss = hh ? 0.0f : dw;
    float a0 = ss * bf_lo(su.x);
    float a1 = ss * bf_hi(su.x);
    float a2 = ss * bf_lo(su.y);
    float a3 = ss * bf_hi(su.y);

    int j = 0;
    for (; j + 7 < c; j += 8) {          // 4 pairs per iteration (8 edges)
        int s[4]; float es[4]; uint2 uu[4];
#pragma unroll
        for (int q = 0; q < 4; ++q) s[q] = eidx[offs + j + 2 * q + hh];
#pragma unroll
        for (int q = 0; q < 4; ++q) es[q] = dinv[s[q]];
#pragma unroll
        for (int q = 0; q < 4; ++q) uu[q] = hrow[(long long)s[q] * 32 + l5];
#pragma unroll
        for (int q = 0; q < 4; ++q) {
            a0 = fmaf(es[q], bf_lo(uu[q].x), a0);
            a1 = fmaf(es[q], bf_hi(uu[q].x), a1);
            a2 = fmaf(es[q], bf_lo(uu[q].y), a2);
            a3 = fmaf(es[q], bf_hi(uu[q].y), a3);
        }
    }
    for (; j + 1 < c; j += 2) {          // single pair
        int s0 = eidx[offs + j + hh];
        float e0 = dinv[s0];
        uint2 u0 = hrow[(long long)s0 * 32 + l5];
        a0 = fmaf(e0, bf_lo(u0.x), a0);
        a1 = fmaf(e0, bf_hi(u0.x), a1);
        a2 = fmaf(e0, bf_lo(u0.y), a2);
        a3 = fmaf(e0, bf_hi(u0.y), a3);
    }
    if (j < c) {                          // odd tail: low half only
        int s0 = eidx[offs + j];
        float e0 = hh ? 0.0f : dinv[s0];
        uint2 u0 = hrow[(long long)s0 * 32 + l5];
        a0 = fmaf(e0, bf_lo(u0.x), a0);
        a1 = fmaf(e0, bf_hi(u0.x), a1);
        a2 = fmaf(e0, bf_lo(u0.y), a2);
        a3 = fmaf(e0, bf_hi(u0.y), a3);
    }

    // combine the two halves before the nonlinearity
    a0 += __shfl_xor(a0, 32);
    a1 += __shfl_xor(a1, 32);
    a2 += __shfl_xor(a2, 32);
    a3 += __shfl_xor(a3, 32);

    float4 bb = ((const float4*)b1)[l5];
    float4 ww = ((const float4*)W2)[l5];
    float r0 = fmaxf(fmaf(dw, a0, bb.x), 0.0f);
    float r1 = fmaxf(fmaf(dw, a1, bb.y), 0.0f);
    float r2 = fmaxf(fmaf(dw, a2, bb.z), 0.0f);
    float r3 = fmaxf(fmaf(dw, a3, bb.w), 0.0f);
    float v = r0 * ww.x + r1 * ww.y + r2 * ww.z + r3 * ww.w;
#pragma unroll
    for (int off = 16; off > 0; off >>= 1) v += __shfl_down(v, off);
    if (lane == 0) zs[w] = v * dw;
}

// ---------------- layer-2 aggregation + sigmoid epilogue (ILP-4) ----------------
__global__ void k_agg2_final(const int* __restrict__ eidx,
                             const int* __restrict__ excl,   // absolute
                             const int* __restrict__ cnt,
                             const float* __restrict__ zs,
                             const float* __restrict__ dinv,
                             const float* __restrict__ b2,
                             float* __restrict__ out) {
    int i = blockIdx.x * 256 + threadIdx.x;
    if (i >= NN) return;
    int offs = excl[i];
    int c = cnt[i];
    float v = zs[i];   // self-loop
    int j = 0;
    for (; j + 3 < c; j += 4) {
        int s0 = eidx[offs + j + 0];
        int s1 = eidx[offs + j + 1];
        int s2 = eidx[offs + j + 2];
        int s3 = eidx[offs + j + 3];
        v += zs[s0] + zs[s1] + zs[s2] + zs[s3];
    }
    for (; j < c; ++j) v += zs[eidx[offs + j]];
    float z = fmaf(dinv[i], v, b2[0]);
    out[i] = 1.0f / (1.0f + __expf(-z));
}

extern "C" void kernel_launch(void* const* d_in, const int* in_sizes, int n_in,
                              void* d_out, int out_size, void* d_ws, size_t ws_size,
                              hipStream_t stream) {
    const float* x  = (const float*)d_in[0];
    const int*   ei = (const int*)d_in[1];
    const float* W1 = (const float*)d_in[2];
    const float* b1 = (const float*)d_in[3];
    const float* W2 = (const float*)d_in[4];
    const float* b2 = (const float*)d_in[5];
    float* out = (float*)d_out;

    const int E = in_sizes[1] / 2;
    const int* src = ei;
    const int* dst = ei + E;

    // workspace layout (4-byte units; bucketArr 8B-aligned, hs 16B-aligned)
    int* wsi = (int*)d_ws;
    float* dinv       = (float*)wsi;                 // N
    int*   cnt        = wsi + NN;                    // N
    int*   excl       = cnt + NN;                    // N
    float* zs         = (float*)(excl + NN);         // N
    int*   bucketFill = (int*)(zs + NN);             // 256
    unsigned short* W1p = (unsigned short*)(bucketFill + 256);  // 32768 bf16 (= 16384 ints)
    int*   eidx       = (int*)(W1p + 32768);         // E
    int2*  bucketArr  = (int2*)(eidx + E);           // NB_BUCKET*BCAP pairs (~19.3 MB)
    unsigned short* hs = (unsigned short*)(bucketArr + (long long)NB_BUCKET * BCAP);  // N*128 bf16

    const int nb_nodes = (NN + 255) / 256;
    const int pa_nb = (E + PA_EDGES - 1) / PA_EDGES;

    hipMemsetAsync(bucketFill, 0, NB_BUCKET * sizeof(int), stream);

    // launch 1: prepW (64 blocks) || partA (pa_nb blocks) — independent roots
    k_prep_partA<<<PREP_NB + pa_nb, 512, 0, stream>>>(W1, W1p, src, dst, E,
                                                      bucketFill, bucketArr);
    // launch 2: partB (196 blocks) || gemm (1563 blocks) — independent chains overlap
    k_gemm_partB<<<NB_BUCKET + GEMM_NB, 512, 0, stream>>>(x, W1p, hs, bucketFill, bucketArr,
                                                          cnt, excl, dinv, eidx);

    k_agg1l2<<<(NN * 64 + 255) / 256, 256, 0, stream>>>(eidx, excl, cnt,
                                                        (const unsigned*)hs, dinv, b1, W2, zs);

    k_agg2_final<<<nb_nodes, 256, 0, stream>>>(eidx, excl, cnt, zs, dinv, b2, out);
}